// Round 7
// baseline (55.614 us; speedup 1.0000x reference)
//
#include <hip/hip_runtime.h>
#include <stdint.h>
#include <stddef.h>

typedef _Float16 f16;
typedef _Float16 f16x2 __attribute__((ext_vector_type(2)));
typedef _Float16 f16x4 __attribute__((ext_vector_type(4)));
typedef _Float16 f16x8 __attribute__((ext_vector_type(8)));
typedef float f32x16 __attribute__((ext_vector_type(16)));

#define INNER_SZ 4225
#define WK 4224          // padded K: 4096 quad + 64 linear + 64 zero
#define KQ 4096
#define XSTR 72          // xs leading-dim pad

// ---------------- prep: fold ones-column, cast W to f16 ----------------
__global__ __launch_bounds__(256) void cm_prep(const float* __restrict__ W,
                                               const float* __restrict__ bias,
                                               f16* __restrict__ Wf,
                                               float* __restrict__ cvec) {
  int idx = blockIdx.x * 256 + threadIdx.x;
  if (idx < 64 * WK) {
    int o = idx / WK;
    int k = idx - o * WK;
    float v;
    if (k < KQ) {                       // quadratic: coeff of x_i * x_j
      int i = k >> 6, j = k & 63;
      v = W[o * INNER_SZ + (i + 1) * 65 + (j + 1)];
    } else if (k < KQ + 64) {           // linear: coeff of x_j
      int j = k - KQ;
      v = W[o * INNER_SZ + (j + 1)] + W[o * INNER_SZ + (j + 1) * 65];
    } else {
      v = 0.f;                          // pad
    }
    Wf[idx] = (f16)v;
  }
  if (idx < 64) cvec[idx] = W[idx * INNER_SZ] + bias[idx];  // const + bias
}

// global -> LDS direct, 16B/lane (dest is wave-uniform base + lane*16)
__device__ inline void gload_lds16(const void* gp, void* lp) {
  __builtin_amdgcn_global_load_lds(
      (const __attribute__((address_space(1))) uint32_t*)(uintptr_t)gp,
      (__attribute__((address_space(3))) uint32_t*)(uintptr_t)lp, 16, 0, 0);
}

// ---------------- main fused kernel ----------------
// grid 512 x 512 threads (8 waves). Block tile: 128 rows x 64 cols.
// Wave (mg=w&3, ng=w>>2): rows mg*32+[0,32), cols ng*32+[0,32); one 32x32x16 MFMA acc.
// 8-phase-style schedule (m201 template): per i-chunk phase =
//   {ds_read 4 B-frags + u16 x_i prefetch + A-build + stage(t+3)} ->
//   vmcnt(2) -> s_barrier -> lgkmcnt(0)+sched_barrier -> setprio(1) ->
//   4 pure MFMAs -> setprio(0) -> s_barrier.
__global__ __launch_bounds__(512, 4) void cm_main(
    const float* __restrict__ x, const f16* __restrict__ Wf,
    const float* __restrict__ cvec, const float* __restrict__ gamma,
    const float* __restrict__ beta, float* __restrict__ out) {
  __shared__ __align__(16) f16 xs[128 * XSTR];   // 18432 B; aliased as `part` in epilogue
  __shared__ __align__(16) f16 wbuf[4][4096];    // 4 slots x 8192 B ring

  const int tid = threadIdx.x;
  const int lane = tid & 63;
  const int w = tid >> 6;
  const int h = lane >> 5;
  const int c31 = lane & 31;
  const int mg = w & 3;
  const int ng = w >> 2;
  const int mbase = blockIdx.x * 128;

  // staging: wave w stages cols [8w, 8w+8) of each chunk (1 x 1KB DMA), pre-swizzled src
  const int scol = w * 8 + (lane >> 3);
  const int sgran = ((lane & 7) ^ (lane >> 3)) * 8;   // f16 units
  const f16* gsrc = Wf + (size_t)scol * WK + sgran;

#define STAGE(T, S) gload_lds16(gsrc + (T) * 64, (char*)&wbuf[(S)][0] + w * 1024)

  // ---- prologue: start W pipeline (3 ahead), stage x tile to LDS ----
  STAGE(0, 0);
  STAGE(1, 1);
  STAGE(2, 2);

#pragma unroll
  for (int it = 0; it < 4; ++it) {
    int off = it * 2048 + tid * 4;
    int row = off >> 6;
    int colx = off & 63;
    const float4 v = *(const float4*)(x + (size_t)(mbase + row) * 64 + colx);
    f16x4 hh = {(f16)v.x, (f16)v.y, (f16)v.z, (f16)v.w};
    *(f16x4*)(xs + row * XSTR + colx) = hh;
  }
  __syncthreads();   // xs visible; drains DMA 0..2 (prologue only)

  const int row = mg * 32 + c31;
  const f16* xsrow = xs + row * XSTR;

  // per-lane j-windows: xjw[s] = x[row, s*16 + h*8 .. +7]   (A k-layout: k=(l>>5)*8+e)
  f16x8 xjw0 = *(const f16x8*)(xsrow + 0 * 16 + h * 8);
  f16x8 xjw1 = *(const f16x8*)(xsrow + 1 * 16 + h * 8);
  f16x8 xjw2 = *(const f16x8*)(xsrow + 2 * 16 + h * 8);
  f16x8 xjw3 = *(const f16x8*)(xsrow + 3 * 16 + h * 8);

  // B-frag byte offsets within a slot (conflict-free swizzled), slot adds imm
  const int col = ng * 32 + c31;
  const int sw = (lane & 7) << 4;
  const int bfo0 = col * 128 + ((0 * 32 + h * 16) ^ sw);
  const int bfo1 = col * 128 + ((1 * 32 + h * 16) ^ sw);
  const int bfo2 = col * 128 + ((2 * 32 + h * 16) ^ sw);
  const int bfo3 = col * 128 + ((3 * 32 + h * 16) ^ sw);

  f32x16 acc = (f32x16)(0.0f);
  uint32_t uraw = *(const uint16_t*)(xsrow + 0);    // x_i(0) prefetch

#define MKA(A, XV)                                                         \
  do {                                                                     \
    f16x8 xv_ = (XV);                                                      \
    _Pragma("unroll") for (int e_ = 0; e_ < 4; ++e_)                       \
        ((f16x2*)&(A))[e_] = spv_ * ((f16x2*)&xv_)[e_];                    \
  } while (0)

#define PHASE(T, DOSTG, VMSTR)                                             \
  {                                                                        \
    const char* wb_ = (const char*)&wbuf[(T) & 3][0];                      \
    f16x8 bf0_ = *(const f16x8*)(wb_ + bfo0);                              \
    f16x8 bf1_ = *(const f16x8*)(wb_ + bfo1);                              \
    f16x8 bf2_ = *(const f16x8*)(wb_ + bfo2);                              \
    f16x8 bf3_ = *(const f16x8*)(wb_ + bfo3);                              \
    uint32_t sp_ = uraw | (uraw << 16);                                    \
    f16x2 spv_ = __builtin_bit_cast(f16x2, sp_);                           \
    f16x8 a0_, a1_, a2_, a3_;                                              \
    MKA(a0_, xjw0); MKA(a1_, xjw1); MKA(a2_, xjw2); MKA(a3_, xjw3);        \
    uraw = *(const uint16_t*)(xsrow + (T) + 1);                            \
    if (DOSTG) STAGE((T) + 3, ((T) + 3) & 3);                              \
    asm volatile("s_waitcnt vmcnt(" VMSTR ")" ::: "memory");               \
    __builtin_amdgcn_s_barrier();                                          \
    asm volatile("s_waitcnt lgkmcnt(0)" ::: "memory");                     \
    __builtin_amdgcn_sched_barrier(0);                                     \
    __builtin_amdgcn_s_setprio(1);                                         \
    acc = __builtin_amdgcn_mfma_f32_32x32x16_f16(a0_, bf0_, acc, 0, 0, 0); \
    acc = __builtin_amdgcn_mfma_f32_32x32x16_f16(a1_, bf1_, acc, 0, 0, 0); \
    acc = __builtin_amdgcn_mfma_f32_32x32x16_f16(a2_, bf2_, acc, 0, 0, 0); \
    acc = __builtin_amdgcn_mfma_f32_32x32x16_f16(a3_, bf3_, acc, 0, 0, 0); \
    __builtin_amdgcn_s_setprio(0);                                         \
    __builtin_amdgcn_s_barrier();                                          \
  }

  // ---- 64 quad phases (i = 0..63) + 1 linear phase ----
#pragma unroll
  for (int T = 0; T < 60; ++T) PHASE(T, 1, "2")
  PHASE(60, 1, "2")   // stages chunk 63
  PHASE(61, 1, "2")   // stages chunk 64 (linear) -> slot 0
  PHASE(62, 0, "1")
  PHASE(63, 0, "0")
  // linear phase: k' = 4096 + j, A = x_j directly; slot 0
  {
    const char* wb_ = (const char*)&wbuf[0][0];
    f16x8 bf0_ = *(const f16x8*)(wb_ + bfo0);
    f16x8 bf1_ = *(const f16x8*)(wb_ + bfo1);
    f16x8 bf2_ = *(const f16x8*)(wb_ + bfo2);
    f16x8 bf3_ = *(const f16x8*)(wb_ + bfo3);
    asm volatile("s_waitcnt lgkmcnt(0)" ::: "memory");
    __builtin_amdgcn_sched_barrier(0);
    __builtin_amdgcn_s_setprio(1);
    acc = __builtin_amdgcn_mfma_f32_32x32x16_f16(xjw0, bf0_, acc, 0, 0, 0);
    acc = __builtin_amdgcn_mfma_f32_32x32x16_f16(xjw1, bf1_, acc, 0, 0, 0);
    acc = __builtin_amdgcn_mfma_f32_32x32x16_f16(xjw2, bf2_, acc, 0, 0, 0);
    acc = __builtin_amdgcn_mfma_f32_32x32x16_f16(xjw3, bf3_, acc, 0, 0, 0);
    __builtin_amdgcn_s_setprio(0);
  }

  // ---- epilogue: +const, LayerNorm over 64 cols, store f32 ----
  // D layout (32x32): col = lane&31, row_local = (r&3) + 8*(r>>2) + 4*h
  const float cv = cvec[col];
  const float gv = gamma[col];
  const float bvt = beta[col];

  float yv[16];
#pragma unroll
  for (int r = 0; r < 16; ++r) yv[r] = acc[r] + cv;

  __syncthreads();               // all waves done with xs/wbuf -> safe to alias
  float* part = (float*)xs;      // [2 ng][128 rows][2] (sum, sumsq)

#pragma unroll
  for (int r = 0; r < 16; ++r) {
    float sv = yv[r];
    float qv = yv[r] * yv[r];
#pragma unroll
    for (int m = 1; m <= 16; m <<= 1) {
      sv += __shfl_xor(sv, m);
      qv += __shfl_xor(qv, m);
    }
    if (c31 == 0) {
      int rl = (r & 3) + 8 * (r >> 2) + 4 * h;
      part[(ng * 128 + mg * 32 + rl) * 2 + 0] = sv;
      part[(ng * 128 + mg * 32 + rl) * 2 + 1] = qv;
    }
  }
  __syncthreads();
#pragma unroll
  for (int r = 0; r < 16; ++r) {
    int rl = (r & 3) + 8 * (r >> 2) + 4 * h;
    int grow = mg * 32 + rl;
    float sv = part[grow * 2 + 0] + part[(128 + grow) * 2 + 0];
    float qv = part[grow * 2 + 1] + part[(128 + grow) * 2 + 1];
    float mean = sv * 0.015625f;
    float var = qv * 0.015625f - mean * mean;
    float rstd = rsqrtf(var + 1e-6f);
    out[(size_t)(mbase + grow) * 64 + col] = gv * (yv[r] - mean) * rstd + bvt;
  }
#undef STAGE
#undef MKA
#undef PHASE
}

extern "C" void kernel_launch(void* const* d_in, const int* in_sizes, int n_in,
                              void* d_out, int out_size, void* d_ws, size_t ws_size,
                              hipStream_t stream) {
  const float* x     = (const float*)d_in[0];
  const float* W     = (const float*)d_in[1];
  const float* bias  = (const float*)d_in[2];
  const float* gamma = (const float*)d_in[3];
  const float* beta  = (const float*)d_in[4];
  float* out = (float*)d_out;

  f16* Wf = (f16*)d_ws;                                  // 64*4224*2 = 540672 B
  float* cvec = (float*)((char*)d_ws + 64 * WK * 2);     // 64 f32

  cm_prep<<<(64 * WK + 255) / 256, 256, 0, stream>>>(W, bias, Wf, cvec);
  cm_main<<<512, 512, 0, stream>>>(x, Wf, cvec, gamma, beta, out);
}

// Round 8
// 44.202 us; speedup vs baseline: 1.2582x; 1.2582x over previous
//
#include <hip/hip_runtime.h>
#include <stdint.h>
#include <stddef.h>

typedef _Float16 f16;
typedef _Float16 f16x2 __attribute__((ext_vector_type(2)));
typedef _Float16 f16x8 __attribute__((ext_vector_type(8)));
typedef float f32x16 __attribute__((ext_vector_type(16)));
typedef uint32_t u32x4 __attribute__((ext_vector_type(4)));

#define INNER_SZ 4225
#define NQ 164          // ksteps: 160 quad (sym-folded, row-rounded) + 4 linear
#define RING 8
#define DEPTH 4

// ---------------- prep: symmetric fold + granule-swizzled f16 pack ----------------
// Wf2 layout: [q][2048B] = [q][ng(2)][64 granules(16B)][8 f16].
// Granule slot P holds logical (col c, half h) with P = (2c+h) ^ ((c>>2)&7)
// (involution-recoverable: G = P ^ ((P>>3)&7); c=G>>1; h=G&1).
// kstep q<160: row i, sub s: coeff[j = s*16 + h*8 + e] =
//   j<i: W[o][i,j]+W[o][j,i] ; j==i: W[o][i,i] ; j>i: 0   (indices +1 / *65 for ones-col)
// kstep 160..163: linear terms W[o][0,j]+W[o][j,0].
__global__ __launch_bounds__(256) void cm_prep(const float* __restrict__ W,
                                               const float* __restrict__ bias,
                                               f16* __restrict__ Wf2,
                                               float* __restrict__ cvec) {
  int idx = blockIdx.x * 256 + threadIdx.x;
  if (idx < NQ * 1024) {
    int q   = idx >> 10;
    int r10 = idx & 1023;
    int ngh = r10 >> 9;
    int rr  = r10 & 511;
    int P   = rr >> 3;
    int e   = rr & 7;
    int G = P ^ ((P >> 3) & 7);
    int c = G >> 1, h = G & 1;
    int o = ngh * 32 + c;
    int kl = h * 8 + e;
    float v = 0.f;
    if (q < 160) {
      int b, start;
      if (q < 16)      { b = 0; start = 0;  }
      else if (q < 48) { b = 1; start = 16; }
      else if (q < 96) { b = 2; start = 48; }
      else             { b = 3; start = 96; }
      int rel = q - start;
      int i = 16 * b + rel / (b + 1);
      int s = rel % (b + 1);
      int j = s * 16 + kl;
      if (j < i)
        v = W[o * INNER_SZ + (i + 1) * 65 + (j + 1)] +
            W[o * INNER_SZ + (j + 1) * 65 + (i + 1)];
      else if (j == i)
        v = W[o * INNER_SZ + (i + 1) * 65 + (i + 1)];
    } else {
      int j = (q - 160) * 16 + kl;
      v = W[o * INNER_SZ + (j + 1)] + W[o * INNER_SZ + (j + 1) * 65];
    }
    Wf2[idx] = (f16)v;
  }
  if (idx < 64) cvec[idx] = W[idx * INNER_SZ] + bias[idx];
}

// global -> LDS direct, 16B/lane
__device__ inline void gload_lds16(const void* gp, void* lp) {
  __builtin_amdgcn_global_load_lds(
      (const __attribute__((address_space(1))) uint32_t*)(uintptr_t)gp,
      (__attribute__((address_space(3))) uint32_t*)(uintptr_t)lp, 16, 0, 0);
}

__device__ constexpr int qb(int i) {   // kstep base of quad row i
  int b = i >> 4;
  return 16 * (b * (b + 1) / 2) + (i & 15) * (b + 1);
}

__device__ inline f16x8 mulsp(f16x2 sp, f16x8 wv) {
  f16x8 r;
#pragma unroll
  for (int e = 0; e < 4; ++e)
    ((f16x2*)&r)[e] = sp * ((const f16x2*)&wv)[e];
  return r;
}

#define WAITVM(N) do { int n_ = (N); \
  if (n_ <= 0)      asm volatile("s_waitcnt vmcnt(0)" ::: "memory"); \
  else if (n_ == 1) asm volatile("s_waitcnt vmcnt(1)" ::: "memory"); \
  else if (n_ == 2) asm volatile("s_waitcnt vmcnt(2)" ::: "memory"); \
  else              asm volatile("s_waitcnt vmcnt(3)" ::: "memory"); } while (0)

#define WAITLGKM(N) do { if ((N) == 0) asm volatile("s_waitcnt lgkmcnt(0)" ::: "memory"); \
                         else          asm volatile("s_waitcnt lgkmcnt(1)" ::: "memory"); } while (0)

// ---------------- main fused kernel ----------------
// grid 1024 x 128 threads (2 waves). Block tile: 64 rows x 64 cols.
// Wave w covers all 64 rows x cols [32w, 32w+32): two 32x32x16 MFMA accs (row-halves).
// Wave-private W staging (ring-8 x 1KB, depth-4 counted vmcnt) -> ZERO barriers in K-loop.
// x held fully in registers (2 rows x 64 f16); A built by splat x_i * fixed window regs.
__global__ __launch_bounds__(128, 2) void cm_main(
    const float* __restrict__ x, const f16* __restrict__ Wf2,
    const float* __restrict__ cvec, const float* __restrict__ gamma,
    const float* __restrict__ beta, float* __restrict__ out) {
  __shared__ union {
    f16 ring[2][RING * 512];   // per-wave 8 slots x 1KB
    float yt[4096];            // epilogue: 64 cols x 64 rows, swizzled (aliases ring)
  } sm;

  const int tid = threadIdx.x;
  const int lane = tid & 63;
  const int w = tid >> 6;            // ng: col-half owner
  const int c31 = lane & 31;
  const int h = lane >> 5;
  const long mbase = (long)blockIdx.x * 64;

  // ---- staging pointers (pre-swizzled source; linear DMA dest) ----
  const char* wsrc = (const char*)Wf2 + w * 1024 + lane * 16;
  char* ringb = (char*)&sm.ring[w][0];
#define STAGE(Q) gload_lds16(wsrc + (size_t)(Q) * 2048, ringb + ((Q) & 7) * 1024)

  STAGE(0); STAGE(1); STAGE(2); STAGE(3);

  // ---- x: 2 full rows into registers (64 u32 = 64 f16x2) ----
  uint32_t xfu[2][32];
#pragma unroll
  for (int rr = 0; rr < 2; ++rr) {
    const float* xr = x + (size_t)(mbase + rr * 32 + c31) * 64;
#pragma unroll
    for (int g = 0; g < 8; ++g) {
      float4 a = *(const float4*)(xr + g * 8);
      float4 b = *(const float4*)(xr + g * 8 + 4);
      f16x2 p0 = {(f16)a.x, (f16)a.y}, p1 = {(f16)a.z, (f16)a.w};
      f16x2 p2 = {(f16)b.x, (f16)b.y}, p3 = {(f16)b.z, (f16)b.w};
      xfu[rr][g * 4 + 0] = __builtin_bit_cast(uint32_t, p0);
      xfu[rr][g * 4 + 1] = __builtin_bit_cast(uint32_t, p1);
      xfu[rr][g * 4 + 2] = __builtin_bit_cast(uint32_t, p2);
      xfu[rr][g * 4 + 3] = __builtin_bit_cast(uint32_t, p3);
    }
  }
  // A-windows: xw[rr][s] = x[row, s*16 + h*8 .. +8)  (lane-half selects granule 2s+h)
  f16x8 xw[2][4];
#pragma unroll
  for (int rr = 0; rr < 2; ++rr)
#pragma unroll
    for (int s = 0; s < 4; ++s) {
      u32x4 t;
#pragma unroll
      for (int k = 0; k < 4; ++k)
        t[k] = h ? xfu[rr][(2 * s + 1) * 4 + k] : xfu[rr][(2 * s) * 4 + k];
      xw[rr][s] = __builtin_bit_cast(f16x8, t);
    }

  // B-read per-lane pointer: granule P = (2c+h)^((c>>2)&7)
  const int P = (2 * c31 + h) ^ ((c31 >> 2) & 7);
  const char* bptr = ringb + P * 16;

  asm volatile("s_waitcnt vmcnt(0)" ::: "memory");   // slots 0..3 + x landed
  f16x8 bA = *(const f16x8*)(bptr + 0 * 1024);
  f16x8 bB;

  f32x16 acc0 = (f32x16)(0.0f);
  f32x16 acc1 = (f32x16)(0.0f);
  f16x2 sp0, sp1;

#define KSTEP(Q, S, LIN)                                                      \
  {                                                                           \
    if ((Q) + DEPTH <= NQ - 1) STAGE((Q) + DEPTH);                            \
    f16x8 a0_, a1_;                                                           \
    if (LIN) { a0_ = xw[0][(S)]; a1_ = xw[1][(S)]; }                          \
    else     { a0_ = mulsp(sp0, xw[0][(S)]); a1_ = mulsp(sp1, xw[1][(S)]); }  \
    if ((Q) < NQ - 1) {                                                       \
      WAITVM((NQ - 2 - (Q)) < (DEPTH - 1) ? (NQ - 2 - (Q)) : (DEPTH - 1));    \
      if ((Q) & 1) bA = *(const f16x8*)(bptr + (((Q) + 1) & 7) * 1024);       \
      else         bB = *(const f16x8*)(bptr + (((Q) + 1) & 7) * 1024);       \
      WAITLGKM(1);                                                            \
    } else {                                                                  \
      WAITLGKM(0);                                                            \
    }                                                                         \
    __builtin_amdgcn_sched_barrier(0);                                        \
    f16x8 bc_ = ((Q) & 1) ? bB : bA;                                          \
    acc0 = __builtin_amdgcn_mfma_f32_32x32x16_f16(a0_, bc_, acc0, 0, 0, 0);   \
    acc1 = __builtin_amdgcn_mfma_f32_32x32x16_f16(a1_, bc_, acc1, 0, 0, 0);   \
  }

  // ---- barrier-free K-loop: 64 quad rows (1-4 ksteps each) + 4 linear ----
#pragma unroll
  for (int I = 0; I < 64; ++I) {
    {  // splat x_i for both row-slots (compile-time register extract)
      uint32_t u0 = xfu[0][I >> 1], u1 = xfu[1][I >> 1];
      if (I & 1) { u0 >>= 16; u1 >>= 16; }
      u0 &= 0xffffu; u1 &= 0xffffu;
      sp0 = __builtin_bit_cast(f16x2, u0 | (u0 << 16));
      sp1 = __builtin_bit_cast(f16x2, u1 | (u1 << 16));
    }
#pragma unroll
    for (int S = 0; S <= (I >> 4); ++S) KSTEP(qb(I) + S, S, 0)
  }
  KSTEP(160, 0, 1) KSTEP(161, 1, 1) KSTEP(162, 2, 1) KSTEP(163, 3, 1)

  // ---- epilogue: transpose via swizzled LDS tile, LN over 64 cols, store ----
  __syncthreads();                       // both waves done with their rings
  {
    const int cg = w * 32 + c31;         // global col
    const int swz = (c31 & 7) << 4;
#pragma unroll
    for (int rq = 0; rq < 4; ++rq) {
      // acc regs 4rq..4rq+3 = rows (rq*8 + 4h) + 0..3 of row-half rr
      int b0 = cg * 256 + 0 * 128 + rq * 32 + h * 16;
      int b1 = cg * 256 + 1 * 128 + rq * 32 + h * 16;
      *(float4*)((char*)sm.yt + (b0 ^ swz)) =
          make_float4(acc0[rq * 4 + 0], acc0[rq * 4 + 1], acc0[rq * 4 + 2], acc0[rq * 4 + 3]);
      *(float4*)((char*)sm.yt + (b1 ^ swz)) =
          make_float4(acc1[rq * 4 + 0], acc1[rq * 4 + 1], acc1[rq * 4 + 2], acc1[rq * 4 + 3]);
    }
  }
  __syncthreads();
  {
    int row = tid >> 1, half = tid & 1;
    float y[32];
    float s = 0.f, qs = 0.f;
#pragma unroll
    for (int j = 0; j < 32; ++j) {
      int c = half * 32 + j;
      int byte = (c * 256 + row * 4) ^ ((c & 7) << 4);
      float v = *(const float*)((const char*)sm.yt + byte);
      v += cvec[c];
      y[j] = v;
      s += v; qs += v * v;
    }
    s  += __shfl_xor(s, 1);
    qs += __shfl_xor(qs, 1);
    float mean = s * 0.015625f;
    float var = qs * 0.015625f - mean * mean;
    float rstd = rsqrtf(var + 1e-6f);
#pragma unroll
    for (int j = 0; j < 32; ++j) {
      int c = half * 32 + j;
      y[j] = gamma[c] * (y[j] - mean) * rstd + beta[c];
    }
    float* op = out + (size_t)(mbase + row) * 64 + half * 32;
#pragma unroll
    for (int j4 = 0; j4 < 8; ++j4)
      *(float4*)(op + j4 * 4) =
          make_float4(y[j4 * 4 + 0], y[j4 * 4 + 1], y[j4 * 4 + 2], y[j4 * 4 + 3]);
  }
#undef STAGE
#undef KSTEP
}

extern "C" void kernel_launch(void* const* d_in, const int* in_sizes, int n_in,
                              void* d_out, int out_size, void* d_ws, size_t ws_size,
                              hipStream_t stream) {
  const float* x     = (const float*)d_in[0];
  const float* W     = (const float*)d_in[1];
  const float* bias  = (const float*)d_in[2];
  const float* gamma = (const float*)d_in[3];
  const float* beta  = (const float*)d_in[4];
  float* out = (float*)d_out;

  f16* Wf2 = (f16*)d_ws;                                   // 164*1024*2 = 335872 B
  float* cvec = (float*)((char*)d_ws + NQ * 1024 * 2);     // 64 f32

  cm_prep<<<(NQ * 1024 + 255) / 256, 256, 0, stream>>>(W, bias, Wf2, cvec);
  cm_main<<<1024, 128, 0, stream>>>(x, Wf2, cvec, gamma, beta, out);
}